// Round 3
// baseline (1039.781 us; speedup 1.0000x reference)
//
#include <hip/hip_runtime.h>

#define SEQ    256
#define FEAT   768
#define WIN    3
#define FILT   6
#define KTOT   (WIN * FEAT)      // 2304
#define WELEMS (KTOT * FILT)     // 13824 floats = 55296 B LDS
#define NB     8                 // batches per wave-group
#define BLOCK  1024
#define NWAVES (BLOCK / 64)      // 16
#define BHALF  128               // batches per block (256 split across 2 blocks)

// Grid = 256 s x 2 batch-halves = 512 blocks. 2 blocks/CU (LDS 2x55.3KB,
// VGPR<=64 via __launch_bounds__(1024,8)) => 32 waves/CU for latency hiding.
// R1 inner loop verbatim (64 VGPR, 0 conflicts, no spills). XCD swizzle maps
// 32 consecutive s (both halves) to one XCD so s-1/s/s+1 share x rows in L2.
__global__ __launch_bounds__(BLOCK, 8)
void pos_linear_kernel(const float* __restrict__ x,
                       const float* __restrict__ W,
                       const float* __restrict__ bias,
                       float* __restrict__ out) {
    __shared__ float wlds[WELEMS];

    // XCD-aware swizzle: consecutive blockIdx round-robin across 8 XCDs.
    // xcd = blk&7 owns s in [xcd*32, xcd*32+32), both batch halves.
    const int blk  = blockIdx.x;
    const int xcd  = blk & 7;
    const int idx  = blk >> 3;           // 0..63
    const int s    = xcd * 32 + (idx & 31);
    const int half = idx >> 5;           // 0 or 1
    const int tid  = threadIdx.x;

    // Stage W[s] -> LDS, float4 coalesced
    {
        const float4* src = (const float4*)(W + (size_t)s * WELEMS);
        float4*       dst = (float4*)wlds;
        for (int i = tid; i < WELEMS / 4; i += BLOCK) dst[i] = src[i];
    }
    __syncthreads();

    const int lane = tid & 63;
    const int wave = tid >> 6;

    // 16 groups of NB=8 batches, exactly one per wave.
    const int b0 = half * BHALF + wave * NB;

    float acc[NB][FILT];
    #pragma unroll
    for (int nb = 0; nb < NB; ++nb)
        #pragma unroll
        for (int o = 0; o < FILT; ++o) acc[nb][o] = 0.f;

    #pragma unroll
    for (int w = 0; w < WIN; ++w) {
        const int r = s - 1 + w;          // original input row
        if (r < 0 || r >= SEQ) continue;  // zero-pad: skip (wave-uniform)
        const float* xrow0 = x + ((size_t)b0 * SEQ + r) * FEAT;
        const float* wbase = wlds + w * FEAT * FILT;

        for (int i = 0; i < FEAT / 64; ++i) {   // 12 iterations
            const int f = lane + 64 * i;

            float wv[FILT];                      // 24 B/lane, stride-6 dwords
            #pragma unroll                       // -> 2-way bank alias (free)
            for (int o = 0; o < FILT; ++o) wv[o] = wbase[f * FILT + o];

            float xv[NB];                        // coalesced dword loads
            #pragma unroll
            for (int nb = 0; nb < NB; ++nb)
                xv[nb] = xrow0[(size_t)nb * SEQ * FEAT + f];

            #pragma unroll
            for (int nb = 0; nb < NB; ++nb)
                #pragma unroll
                for (int o = 0; o < FILT; ++o)
                    acc[nb][o] = fmaf(xv[nb], wv[o], acc[nb][o]);
        }
    }

    // Butterfly reduce all 48 partials across the 64 lanes.
    float vals[NB * FILT];
    #pragma unroll
    for (int nb = 0; nb < NB; ++nb)
        #pragma unroll
        for (int o = 0; o < FILT; ++o) vals[nb * FILT + o] = acc[nb][o];

    #pragma unroll
    for (int m = 1; m < 64; m <<= 1) {
        #pragma unroll
        for (int i = 0; i < NB * FILT; ++i)
            vals[i] += __shfl_xor(vals[i], m, 64);
    }

    // Every lane now holds all 48 sums; lane L (<48) selects sum #L.
    if (lane < NB * FILT) {
        float v = vals[0];
        #pragma unroll
        for (int i = 1; i < NB * FILT; ++i) v = (lane == i) ? vals[i] : v;
        const int nb = lane / FILT;
        const int o  = lane - nb * FILT;
        v += bias[s * FILT + o];
        v = v > 0.f ? v : 0.f;
        out[((size_t)(b0 + nb) * SEQ + s) * FILT + o] = v;
    }
}

extern "C" void kernel_launch(void* const* d_in, const int* in_sizes, int n_in,
                              void* d_out, int out_size, void* d_ws, size_t ws_size,
                              hipStream_t stream) {
    const float* x   = (const float*)d_in[0];  // (256, 256, 768) fp32
    const float* W   = (const float*)d_in[1];  // (256, 2304, 6) fp32
    const float* b   = (const float*)d_in[2];  // (256, 6) fp32
    float*       out = (float*)d_out;          // (256, 256, 6) fp32
    (void)in_sizes; (void)n_in; (void)out_size; (void)d_ws; (void)ws_size;
    pos_linear_kernel<<<SEQ * 2, BLOCK, 0, stream>>>(x, W, b, out);
}

// Round 4
// 596.840 us; speedup vs baseline: 1.7421x; 1.7421x over previous
//
#include <hip/hip_runtime.h>

#define SEQ    256
#define FEAT   768
#define WIN    3
#define FILT   6
#define KTOT   (WIN * FEAT)      // 2304
#define WELEMS (KTOT * FILT)     // 13824 floats = 55296 B LDS
#define NB     8                 // batches per wave-group
#define BLOCK  1024
#define NWAVES (BLOCK / 64)      // 16
#define BATCH  256
#define NGROUPS (BATCH / NB)     // 32
#define NITER  (FEAT / 64)       // 12

// One block per s, W[s] in LDS (55KB), 16 waves/CU. Empirical gfx950 law
// (R1-R3): VGPR cap = 256/min_waves_per_EU for 1024-thread blocks, so
// (1024,2) => cap 128. R1's (1024,4)=>64 starved the loop to ~1 load in
// flight/wave => 2.2 TB/s (Little's law). Fix: cap 128 + manual double-
// buffered x prefetch => ~8 loads in flight/wave, 16 waves => ~32KB/CU
// outstanding, enough for ~6 TB/s at ~600cyc latency.
__global__ __launch_bounds__(BLOCK, 2)
void pos_linear_kernel(const float* __restrict__ x,
                       const float* __restrict__ W,
                       const float* __restrict__ bias,
                       float* __restrict__ out) {
    __shared__ float wlds[WELEMS];
    const int s   = blockIdx.x;
    const int tid = threadIdx.x;

    // Stage W[s] -> LDS, float4 coalesced
    {
        const float4* src = (const float4*)(W + (size_t)s * WELEMS);
        float4*       dst = (float4*)wlds;
        for (int i = tid; i < WELEMS / 4; i += BLOCK) dst[i] = src[i];
    }
    __syncthreads();

    const int lane = tid & 63;
    const int wave = tid >> 6;

    for (int g = wave; g < NGROUPS; g += NWAVES) {     // 2 groups per wave
        const int b0 = g * NB;

        float acc[NB][FILT];
        #pragma unroll
        for (int nb = 0; nb < NB; ++nb)
            #pragma unroll
            for (int o = 0; o < FILT; ++o) acc[nb][o] = 0.f;

        for (int w = 0; w < WIN; ++w) {
            const int r = s - 1 + w;
            if (r < 0 || r >= SEQ) continue;           // zero-pad (uniform)
            const float* xrow0 = x + ((size_t)b0 * SEQ + r) * FEAT;
            const float* wbase = wlds + w * FEAT * FILT;

            float xv[NB], xn[NB];
            #pragma unroll
            for (int nb = 0; nb < NB; ++nb)            // prologue prefetch
                xn[nb] = xrow0[(size_t)nb * SEQ * FEAT + lane];

            #pragma unroll
            for (int i = 0; i < NITER; ++i) {          // fully unrolled: the
                const int f = lane + 64 * i;           // xv=xn copy vanishes
                #pragma unroll
                for (int nb = 0; nb < NB; ++nb) xv[nb] = xn[nb];

                if (i + 1 < NITER) {                   // prefetch next iter
                    #pragma unroll
                    for (int nb = 0; nb < NB; ++nb)
                        xn[nb] = xrow0[(size_t)nb * SEQ * FEAT + f + 64];
                }

                float wv[FILT];                        // stride-6 dwords ->
                #pragma unroll                         // 2-way alias (free)
                for (int o = 0; o < FILT; ++o) wv[o] = wbase[f * FILT + o];

                #pragma unroll
                for (int nb = 0; nb < NB; ++nb)
                    #pragma unroll
                    for (int o = 0; o < FILT; ++o)
                        acc[nb][o] = fmaf(xv[nb], wv[o], acc[nb][o]);
            }
        }

        // Butterfly reduce all 48 partials across the 64 lanes.
        float vals[NB * FILT];
        #pragma unroll
        for (int nb = 0; nb < NB; ++nb)
            #pragma unroll
            for (int o = 0; o < FILT; ++o) vals[nb * FILT + o] = acc[nb][o];

        #pragma unroll
        for (int m = 1; m < 64; m <<= 1) {
            #pragma unroll
            for (int i = 0; i < NB * FILT; ++i)
                vals[i] += __shfl_xor(vals[i], m, 64);
        }

        if (lane < NB * FILT) {
            float v = vals[0];
            #pragma unroll
            for (int i = 1; i < NB * FILT; ++i) v = (lane == i) ? vals[i] : v;
            const int nb = lane / FILT;
            const int o  = lane - nb * FILT;
            v += bias[s * FILT + o];
            v = v > 0.f ? v : 0.f;
            out[((size_t)(b0 + nb) * SEQ + s) * FILT + o] = v;
        }
    }
}

extern "C" void kernel_launch(void* const* d_in, const int* in_sizes, int n_in,
                              void* d_out, int out_size, void* d_ws, size_t ws_size,
                              hipStream_t stream) {
    const float* x   = (const float*)d_in[0];  // (256, 256, 768) fp32
    const float* W   = (const float*)d_in[1];  // (256, 2304, 6) fp32
    const float* b   = (const float*)d_in[2];  // (256, 6) fp32
    float*       out = (float*)d_out;          // (256, 256, 6) fp32
    (void)in_sizes; (void)n_in; (void)out_size; (void)d_ws; (void)ws_size;
    pos_linear_kernel<<<SEQ, BLOCK, 0, stream>>>(x, W, b, out);
}

// Round 5
// 344.753 us; speedup vs baseline: 3.0160x; 1.7312x over previous
//
#include <hip/hip_runtime.h>

#define SEQ    256
#define FEAT   768
#define WIN    3
#define FILT   6
#define KTOT   (WIN * FEAT)      // 2304
#define WELEMS (KTOT * FILT)     // 13824 floats = 55296 B
#define NB     8                 // batches per wave-group
#define BLOCK  512
#define NWAVES (BLOCK / 64)      // 8
#define BHALF  128               // batches per block

// Grid = 256 s x 2 batch-halves = 512 blocks of 512 threads.
// Empirical gfx950 VGPR law (R1-R4): cap = 256/max(lb_arg, block_waves/4).
// 1024-thread blocks are stuck at 64 VGPR (the R1-R4 latency wall);
// (512,2) => cap 128. Spend it on MLP: 8x global_load_dwordx4 per iter
// (8KB in flight/wave vs 256B in R1). W stored as 18 (w,o)-planes in LDS
// so the per-o read is lane-contiguous ds_read_b128 (conflict-free).
// LDS 55.3KB => 2 blocks/CU => 16 waves/CU.
__global__ __launch_bounds__(BLOCK, 2)
void pos_linear_kernel(const float* __restrict__ x,
                       const float* __restrict__ W,
                       const float* __restrict__ bias,
                       float* __restrict__ out) {
    __shared__ float wl[WIN * FILT * FEAT];   // [(w*6+o)*768 + f], 55296 B

    const int blk  = blockIdx.x;
    const int s    = blk >> 1;
    const int half = blk & 1;
    const int tid  = threadIdx.x;

    // Stage W[s] -> transposed planes. Row k: 6 consecutive floats scatter
    // to 6 planes at f-contiguous addresses (stride-1 per lane: no conflicts).
    for (int k = tid; k < KTOT; k += BLOCK) {
        const int w = k / FEAT, f = k - w * FEAT;
        const float* src = W + (size_t)s * WELEMS + (size_t)k * FILT;
        #pragma unroll
        for (int o = 0; o < FILT; ++o)
            wl[(w * FILT + o) * FEAT + f] = src[o];
    }
    __syncthreads();

    const int lane = tid & 63;
    const int wave = tid >> 6;

    #pragma unroll 1
    for (int gi = 0; gi < 2; ++gi) {          // 16 groups over 8 waves
        const int b0 = half * BHALF + (wave + NWAVES * gi) * NB;

        float acc[NB][FILT];
        #pragma unroll
        for (int nb = 0; nb < NB; ++nb)
            #pragma unroll
            for (int o = 0; o < FILT; ++o) acc[nb][o] = 0.f;

        for (int w = 0; w < WIN; ++w) {
            const int r = s - 1 + w;
            if (r < 0 || r >= SEQ) continue;  // zero-pad (wave-uniform)
            const float* xrow0 = x + ((size_t)b0 * SEQ + r) * FEAT;

            #pragma unroll
            for (int i = 0; i < FEAT / 256; ++i) {   // 3 iters
                const int f4 = lane + 64 * i;        // float4 index in row

                float4 xv[NB];                       // 8x dwordx4, 8KB/wave
                #pragma unroll
                for (int nb = 0; nb < NB; ++nb)
                    xv[nb] = *(const float4*)(xrow0 + (size_t)nb * SEQ * FEAT + 4 * f4);

                #pragma unroll
                for (int o = 0; o < FILT; ++o) {
                    // plane (w,o): lane-contiguous ds_read_b128, no conflicts
                    const float4 wv = *(const float4*)(wl + (w * FILT + o) * FEAT + 4 * f4);
                    const float* wf = (const float*)&wv;
                    #pragma unroll
                    for (int nb = 0; nb < NB; ++nb) {
                        const float* xf = (const float*)&xv[nb];
                        #pragma unroll
                        for (int ff = 0; ff < 4; ++ff)
                            acc[nb][o] = fmaf(xf[ff], wf[ff], acc[nb][o]);
                    }
                }
            }
        }

        // Butterfly reduce all 48 partials across the 64 lanes.
        float vals[NB * FILT];
        #pragma unroll
        for (int nb = 0; nb < NB; ++nb)
            #pragma unroll
            for (int o = 0; o < FILT; ++o) vals[nb * FILT + o] = acc[nb][o];

        #pragma unroll
        for (int m = 1; m < 64; m <<= 1) {
            #pragma unroll
            for (int i = 0; i < NB * FILT; ++i)
                vals[i] += __shfl_xor(vals[i], m, 64);
        }

        if (lane < NB * FILT) {
            float v = vals[0];
            #pragma unroll
            for (int i = 1; i < NB * FILT; ++i) v = (lane == i) ? vals[i] : v;
            const int nb = lane / FILT;
            const int o  = lane - nb * FILT;
            v += bias[s * FILT + o];
            v = v > 0.f ? v : 0.f;
            out[((size_t)(b0 + nb) * SEQ + s) * FILT + o] = v;
        }
    }
}

extern "C" void kernel_launch(void* const* d_in, const int* in_sizes, int n_in,
                              void* d_out, int out_size, void* d_ws, size_t ws_size,
                              hipStream_t stream) {
    const float* x   = (const float*)d_in[0];  // (256, 256, 768) fp32
    const float* W   = (const float*)d_in[1];  // (256, 2304, 6) fp32
    const float* b   = (const float*)d_in[2];  // (256, 6) fp32
    float*       out = (float*)d_out;          // (256, 256, 6) fp32
    (void)in_sizes; (void)n_in; (void)out_size; (void)d_ws; (void)ws_size;
    pos_linear_kernel<<<SEQ * 2, BLOCK, 0, stream>>>(x, W, b, out);
}

// Round 6
// 321.881 us; speedup vs baseline: 3.2303x; 1.0711x over previous
//
#include <hip/hip_runtime.h>

#define SEQ     256
#define FEAT    768
#define WIN     3
#define FILT    6
#define KTOT    (WIN * FEAT)       // 2304
#define WELEMS  (KTOT * FILT)      // 13824 floats = 55296 B
#define NB      8                  // batches per group (all waves together)
#define BLOCK   768                // 12 waves: 3 window-rows x 4 f-quarters
#define NWAVES  12
#define NGROUPS 32
#define RSTR    49                 // reduction row stride (48 + 1 pad)

// One block per s (all resident: 256 blocks, 1/CU). ALL 12 waves process the
// SAME 8-batch group, splitting K: wave = (w, fq), lane owns f = 192*fq+lane
// (+64j, j<3). This caps the per-XCD active x footprint at
// 32 s x 8 b x 34 rows x 3KB = 816KB < 4MB L2, so with the s-contiguous XCD
// swizzle (s = (blk&7)<<5 | blk>>3) each row is fetched once per XCD and hit
// 3x from L2 -> logical L2-miss traffic 604 -> ~225 MB (the R1-R5 144us
// invariant was the ~4.2 TB/s L2-fill service on 604 MB).
// 768-thr block => VGPR cap ~85 (empirical law 256/3): v[48]+xv[8]+wv[6] fits.
__global__ __launch_bounds__(BLOCK, 3)
void pos_linear_kernel(const float* __restrict__ x,
                       const float* __restrict__ W,
                       const float* __restrict__ bias,
                       float* __restrict__ out) {
    __shared__ float wlds[WELEMS];
    __shared__ float red[2][NWAVES * RSTR];   // parity => 1 barrier/group

    const int blk = blockIdx.x;
    const int s   = ((blk & 7) << 5) | (blk >> 3);  // XCD k <- s in [32k,32k+32)
    const int tid = threadIdx.x;

    // Stage W[s] -> LDS, float4 coalesced (R1-proven layout: row-major k*6+o)
    {
        const float4* src = (const float4*)(W + (size_t)s * WELEMS);
        float4*       dst = (float4*)wlds;
        for (int i = tid; i < WELEMS / 4; i += BLOCK) dst[i] = src[i];
    }

    const int lane = tid & 63;
    const int wave = tid >> 6;           // 0..11
    const int w    = wave >> 2;          // window row 0..2
    const int q    = wave & 3;           // f-quarter 0..3
    const int r    = s - 1 + w;          // input row
    const bool valid = (r >= 0) && (r < SEQ);
    const int  f0   = 192 * q + lane;    // this lane's first feature
    const int  k0   = FEAT * w + f0;     // K index into W
    const float* xrow = valid ? (x + (size_t)r * FEAT + f0) : x;

    // R2-verified halving-tree output mapping: lane<16 holds idx 3*bitrev4+j
    const int gidx = ((lane & 1) << 3) | ((lane & 2) << 1) |
                     ((lane & 4) >> 1) | ((lane & 8) >> 3);

    __syncthreads();

    for (int g = 0; g < NGROUPS; ++g) {
        const int b0 = g * NB;

        float v[NB * FILT];              // accumulate directly in v[]
        #pragma unroll
        for (int i = 0; i < NB * FILT; ++i) v[i] = 0.f;

        if (valid) {                     // wave-uniform (edge s skips one w)
            #pragma unroll
            for (int j = 0; j < 3; ++j) {
                const int kj = k0 + 64 * j;
                float wv[FILT];          // stride-24B LDS: 2-way alias, free
                #pragma unroll
                for (int o = 0; o < FILT; ++o) wv[o] = wlds[kj * FILT + o];

                float xv[NB];            // coalesced dwords, 8 in flight
                #pragma unroll
                for (int nb = 0; nb < NB; ++nb)
                    xv[nb] = xrow[(size_t)(b0 + nb) * (SEQ * FEAT) + 64 * j];

                #pragma unroll
                for (int nb = 0; nb < NB; ++nb)
                    #pragma unroll
                    for (int o = 0; o < FILT; ++o)
                        v[nb * FILT + o] = fmaf(xv[nb], wv[o], v[nb * FILT + o]);
            }
        }

        // In-wave halving tree: 48 partials -> lane<16 x 3 values
        #pragma unroll
        for (int step = 0; step < 4; ++step) {
            const int m    = 1 << step;
            const int half = 48 >> (step + 1);     // 24,12,6,3
            const bool upper = (lane & m) != 0;
            #pragma unroll
            for (int j = 0; j < half; ++j) {
                float snd = upper ? v[j] : v[j + half];
                float kep = upper ? v[j + half] : v[j];
                v[j] = kep + __shfl_xor(snd, m, 64);
            }
        }
        #pragma unroll
        for (int j = 0; j < 3; ++j) {
            v[j] += __shfl_xor(v[j], 16, 64);
            v[j] += __shfl_xor(v[j], 32, 64);
        }

        // Cross-wave: write 48 partials per wave, single barrier (parity buf)
        float* rb = red[g & 1];
        if (lane < 16) {
            #pragma unroll
            for (int j = 0; j < 3; ++j)
                rb[wave * RSTR + 3 * gidx + j] = v[j];
        }
        __syncthreads();

        // Rotating finalizer wave sums 12 partials, bias+relu, store.
        const int ft = tid - ((g % NWAVES) << 6);
        if (ft >= 0 && ft < 48) {
            float sum = 0.f;
            #pragma unroll
            for (int vw = 0; vw < NWAVES; ++vw) sum += rb[vw * RSTR + ft];
            const int nb = ft / FILT;
            const int o  = ft - nb * FILT;
            float val = sum + bias[s * FILT + o];
            val = val > 0.f ? val : 0.f;
            out[((size_t)(b0 + nb) * SEQ + s) * FILT + o] = val;
        }
    }
}

extern "C" void kernel_launch(void* const* d_in, const int* in_sizes, int n_in,
                              void* d_out, int out_size, void* d_ws, size_t ws_size,
                              hipStream_t stream) {
    const float* x   = (const float*)d_in[0];  // (256, 256, 768) fp32
    const float* W   = (const float*)d_in[1];  // (256, 2304, 6) fp32
    const float* b   = (const float*)d_in[2];  // (256, 6) fp32
    float*       out = (float*)d_out;          // (256, 256, 6) fp32
    (void)in_sizes; (void)n_in; (void)out_size; (void)d_ws; (void)ws_size;
    pos_linear_kernel<<<SEQ, BLOCK, 0, stream>>>(x, W, b, out);
}